// Round 7
// baseline (1060.178 us; speedup 1.0000x reference)
//
#include <hip/hip_runtime.h>
#include <math.h>

#define NUM_V 512
#define NUM_F 1024
#define IMG_H 256
#define NCHUNK 16
#define FPC (NUM_F/NCHUNK)        // 64 faces per chunk
#define NTILE 256
#define TAN_T 0.57735026919f      // tan(30 deg)
#define LOG_EPS  -13.8155106f     // log(1e-6)
// Edge constants pre-scaled by 100 = sqrt(1/SIGMA), so s = d'*|d'| directly.
#define DCULL_S  -3.72f           // scaled dist <= -3.72 => |term| < 1e-6
#define POISON_I ((int)0xAAAAAAAA)  // harness ws poison pattern as int

// Workspace:
//   slices [NTILE*NCHUNK][256] f32  sparse-written (only chunks with n>0)
//   cnt    [NTILE*NCHUNK] int       plain-stored n by every block
//   done   [1] int                  arrival counter (base = poison or 0)
//
// Single dispatch. Every block: render its (tile,chunk), publish, then
// fence + agent-scope fetch_add(done). The block seeing old==base+4095 is
// the unique last arrival: all 4096 publications happened-before its
// acquire -> it alone runs the SSE tail and plain-stores out[0].
// NO spinning (R6's 334us failure mode was spin-wait coherence storms).

__global__ __launch_bounds__(256, 8) void fused_kernel(
    const float* __restrict__ verts,     // (NUM_V,3)
    const int*   __restrict__ faces,     // (NUM_F,3)
    const float* __restrict__ cam,       // (3,)
    const float* __restrict__ image_ref, // (IMG_H*IMG_H)
    float* __restrict__ slices,
    int*   __restrict__ cnt,
    int*   __restrict__ done,
    float* __restrict__ out)
{
    __shared__ float sx[NUM_V], sy[NUM_V], sz[NUM_V];   // 6 KB
    __shared__ float4 sfA[FPC+4], sfB[FPC+4];
    __shared__ float  sfC[FPC+4];
    __shared__ int   scnt;
    __shared__ int   sLast;
    __shared__ int   smask[NTILE];                      // 1 KB (tail only)
    __shared__ float wsum[4];

    const int tid   = threadIdx.x;
    const int chunk = blockIdx.x & (NCHUNK-1);
    const int tile  = blockIdx.x / NCHUNK;

    if (tid == 0) scnt = 0;

    // ---- camera basis ----
    const float ex = cam[0], ey = cam[1], ez = cam[2];
    float inv = 1.0f / (sqrtf(ex*ex + ey*ey + ez*ez) + 1e-8f);
    const float zx = -ex*inv, zy = -ey*inv, zz = -ez*inv;
    float xxr = zz, xyr = 0.0f, xzr = -zx;    // cross((0,1,0), z)
    inv = 1.0f / (sqrtf(xxr*xxr + xyr*xyr + xzr*xzr) + 1e-8f);
    const float xx = xxr*inv, xy = xyr*inv, xz = xzr*inv;
    float yxr = zy*xz - zz*xy;
    float yyr = zz*xx - zx*xz;
    float yzr = zx*xy - zy*xx;
    inv = 1.0f / (sqrtf(yxr*yxr + yyr*yyr + yzr*yzr) + 1e-8f);
    const float yx = yxr*inv, yy = yyr*inv, yz = yzr*inv;

    // ---- project vertices (2 per thread) ----
    for (int v = tid; v < NUM_V; v += 256) {
        float px = verts[3*v+0] - ex;
        float py = verts[3*v+1] - ey;
        float pz = verts[3*v+2] - ez;
        float vx = xx*px + xy*py + xz*pz;
        float vy = yx*px + yy*py + yz*pz;
        float vz = zx*px + zy*py + zz*pz;
        float denom = 1.0f / (vz*TAN_T + 1e-8f);
        sx[v] = vx*denom;
        sy[v] = vy*denom;
        sz[v] = vz;
    }
    __syncthreads();   // covers scnt init too

    // ---- tile rect (pixel-center corners; d affine -> corners bound it) ----
    const int j0 = (tile & 15) * 16;
    const int i0 = (tile >> 4) * 16;
    const float xL = (j0 + 0.5f )*(2.0f/IMG_H) - 1.0f;
    const float xR = (j0 + 15.5f)*(2.0f/IMG_H) - 1.0f;
    const float yT = 1.0f - (i0 + 0.5f )*(2.0f/IMG_H);
    const float yB = 1.0f - (i0 + 15.5f)*(2.0f/IMG_H);

    // ---- cull + compact this chunk's faces (one per thread, tid<64) ----
    if (tid < FPC) {
        const int f = chunk*FPC + tid;
        int i0f = faces[3*f+0], i1f = faces[3*f+1], i2f = faces[3*f+2];
        float ax = sx[i0f], ay = sy[i0f], z0 = sz[i0f];
        float bx = sx[i1f], by = sy[i1f], z1 = sz[i1f];
        float cx = sx[i2f], cy = sy[i2f], z2 = sz[i2f];
        bool keep = (z0 > 0.001f && z1 > 0.001f && z2 > 0.001f);

        float A[3], B[3], C[3];   // scaled by 100 = sqrt(1/SIGMA)
        const float px_[3] = {ax, bx, cx}, py_[3] = {ay, by, cy};
        const float qx_[3] = {bx, cx, ax}, qy_[3] = {by, cy, ay};
        #pragma unroll
        for (int k = 0; k < 3; ++k) {
            float eex = qx_[k] - px_[k];
            float eey = qy_[k] - py_[k];
            float il = 100.0f / (sqrtf(eex*eex + eey*eey) + 1e-8f);
            A[k] = eex*il;
            B[k] = eey*il;
            C[k] = (eex*py_[k] - eey*px_[k])*il;
        }

        if (keep) {
            // skip iff (min_k max_q d_k <= DCULL_S) && (max_k min_q d_k >= -DCULL_S)
            float minmx = 3.0e38f, maxmn = -3.0e38f;
            #pragma unroll
            for (int k = 0; k < 3; ++k) {
                float dTL = A[k]*yT - B[k]*xL - C[k];
                float dTR = A[k]*yT - B[k]*xR - C[k];
                float dBL = A[k]*yB - B[k]*xL - C[k];
                float dBR = A[k]*yB - B[k]*xR - C[k];
                float mx = fmaxf(fmaxf(dTL, dTR), fmaxf(dBL, dBR));
                float mn = fminf(fminf(dTL, dTR), fminf(dBL, dBR));
                minmx = fminf(minmx, mx);
                maxmn = fmaxf(maxmn, mn);
            }
            keep = !((minmx <= DCULL_S) && (maxmn >= -DCULL_S));
        }
        if (keep) {
            int s = atomicAdd(&scnt, 1);
            sfA[s] = make_float4(A[0], B[0], C[0], A[1]);
            sfB[s] = make_float4(B[1], C[1], A[2], B[2]);
            sfC[s] = C[2];
        }
    }
    __syncthreads();

    const int n = scnt;

    if (n > 0) {
        // pad to multiple of 4 with zero-contribution sentinels
        const int npad = (4 - (n & 3)) & 3;
        if (tid < npad) {
            const int s = n + tid;
            sfA[s] = make_float4(0.0f, 0.0f, 1e30f, 0.0f);
            sfB[s] = make_float4(0.0f, -1e30f, 0.0f, 0.0f);
            sfC[s] = 0.0f;
        }
        __syncthreads();
        const int ng = (n + 3) & ~3;

        // pixel: wave = 8x8 sub-tile
        const int w = tid >> 6, l = tid & 63;
        const int lj = (w & 1)*8 + (l & 7);
        const int li = (w >> 1)*8 + (l >> 3);
        const float qx = (j0 + lj + 0.5f)*(2.0f/IMG_H) - 1.0f;
        const float qy = 1.0f - (i0 + li + 0.5f)*(2.0f/IMG_H);

        float acc = 0.0f;
        for (int g = 0; g < ng; g += 4) {
            float dist4[4];
            #pragma unroll
            for (int u = 0; u < 4; ++u) {
                float4 w0 = sfA[g+u];
                float4 w1 = sfB[g+u];
                float  c2 = sfC[g+u];
                float d0 = fmaf(w0.x, qy, -fmaf(w0.y, qx, w0.z));
                float d1 = fmaf(w0.w, qy, -fmaf(w1.x, qx, w1.y));
                float d2 = fmaf(w1.z, qy, -fmaf(w1.w, qx, c2));
                float dmin = fminf(fminf(d0, d1), d2);
                float dmax = fmaxf(fmaxf(d0, d1), d2);
                dist4[u] = fmaxf(dmin, -dmax);   // = 100 * true dist
            }
            float gm = fmaxf(fmaxf(dist4[0], dist4[1]), fmaxf(dist4[2], dist4[3]));
            if (__any(gm > DCULL_S)) {
                #pragma unroll
                for (int u = 0; u < 4; ++u) {
                    float dist = dist4[u];
                    float s  = dist * fabsf(dist);     // true dist*|dist|/SIGMA
                    float e2 = __builtin_exp2f(-fabsf(s) * 1.44269504f);
                    float lg = __builtin_log2f(1.0f + e2);
                    float sp = fmaf(lg, 0.69314718f, fmaxf(s, 0.0f));
                    acc += fmaxf(-sp, LOG_EPS);
                }
            }
        }
        slices[(tile*NCHUNK + chunk)*256 + li*16 + lj] = acc;
    }

    // ---- publish + arrival (no spinning) ----
    if (tid == 0) cnt[tile*NCHUNK + chunk] = n;
    __syncthreads();   // all slice/cnt stores in this block are issued+drained
    if (tid == 0) {
        __threadfence();
        int old = __hip_atomic_fetch_add(done, 1, __ATOMIC_ACQ_REL,
                                         __HIP_MEMORY_SCOPE_AGENT);
        // unique last arrival under either ws init (0xAA poison or zeroed)
        sLast = (old == POISON_I + 4095) || (old == 4095);
    }
    __syncthreads();
    if (!sLast) return;
    __threadfence();   // acquire: all 4095 publications now visible

    // ---- tail (one block): per-tile nonzero-chunk masks ----
    {
        int m = 0;
        #pragma unroll
        for (int c = 0; c < NCHUNK; ++c)
            if (cnt[tid*NCHUNK + c] > 0) m |= (1 << c);
        smask[tid] = m;
    }
    __syncthreads();

    // thread t handles pixel-index t of every tile
    const int tli = tid >> 4, tlj = tid & 15;
    float sse = 0.0f;
    for (int T = 0; T < NTILE; ++T) {
        int m = smask[T];                       // block-uniform
        float ref = image_ref[((T >> 4)*16 + tli)*IMG_H + (T & 15)*16 + tlj];
        float lsum = 0.0f;
        while (m) {
            int c = __builtin_ffs(m) - 1;
            m &= m - 1;
            lsum += slices[(T*NCHUNK + c)*256 + tid];
        }
        float alpha = 1.0f - __expf(lsum);      // lsum==0 -> alpha==0 exactly
        float diff  = ref - alpha;
        sse += diff * diff;
    }

    #pragma unroll
    for (int off = 32; off > 0; off >>= 1) sse += __shfl_down(sse, off, 64);
    if ((tid & 63) == 0) wsum[tid >> 6] = sse;
    __syncthreads();
    if (tid == 0) {
        float dist = sqrtf(ex*ex + ey*ey + ez*ez);
        float pen  = fmaxf(6.0f - dist, 0.0f);
        float total = (wsum[0] + wsum[1]) + (wsum[2] + wsum[3]);
        out[0] = total * (1.0f + pen);   // single writer, plain store
    }
}

extern "C" void kernel_launch(void* const* d_in, const int* in_sizes, int n_in,
                              void* d_out, int out_size, void* d_ws, size_t ws_size,
                              hipStream_t stream)
{
    const float* verts     = (const float*)d_in[0];  // (1,512,3)
    const int*   faces     = (const int*)  d_in[1];  // (1,1024,3)
    const float* image_ref = (const float*)d_in[2];  // (256,256)
    const float* cam       = (const float*)d_in[3];  // (3,)

    char* ws = (char*)d_ws;
    float* slices = (float*)ws;                                  // 4 MB
    int*   cnt    = (int*)(ws + NTILE*NCHUNK*256*4);             // 16 KB
    int*   done   = (int*)(ws + NTILE*NCHUNK*256*4 + NTILE*NCHUNK*4);
    float* out    = (float*)d_out;

    fused_kernel<<<NTILE*NCHUNK, 256, 0, stream>>>(verts, faces, cam, image_ref,
                                                   slices, cnt, done, out);
}

// Round 8
// 83.498 us; speedup vs baseline: 12.6970x; 12.6970x over previous
//
#include <hip/hip_runtime.h>
#include <math.h>

#define NUM_V 512
#define NUM_F 1024
#define IMG_H 256
#define NCHUNK 16
#define FPC (NUM_F/NCHUNK)        // 64 faces per chunk
#define NTILE 256
#define TPB 4                     // tiles rendered per block
#define NGRP (NTILE/TPB)          // 64 tile-groups
#define TAN_T 0.57735026919f      // tan(30 deg)
#define LOG_EPS  -13.8155106f     // log(1e-6)
// Edge constants pre-scaled by 100 = sqrt(1/SIGMA), so s = d'*|d'| directly.
#define DCULL_S  -3.72f           // scaled dist <= -3.72 => |term| < 1e-6

// Two dispatches (R6/R7 proved single-kernel fusion loses 250-1000us to
// cross-XCD coherence: agent-scope fence/atomic per block ~ L2 wb/inv).
// Render: 64 tile-groups x 16 chunks = 1024 blocks. Each block projects
// verts + builds its chunk's (tile-independent) face constants ONCE in
// registers, then loops over 4 tiles (grp + 64k: 4 tile-rows apart, so at
// most ~1 heavy tile/block): corner-bound cull -> compact -> render.
// Publishes cnt[tile][chunk] (always) + 256-float slice (only if n>0).
// Finalize: per-tile sparse sum, alpha, SSE, one atomicAdd.

__global__ __launch_bounds__(256, 8) void render_kernel(
    const float* __restrict__ verts,   // (NUM_V,3)
    const int*   __restrict__ faces,   // (NUM_F,3)
    const float* __restrict__ cam,     // (3,)
    float* __restrict__ slices,        // NTILE*NCHUNK*256 f32 (sparse-written)
    int*   __restrict__ cnt,           // NTILE*NCHUNK ints (always written)
    float* __restrict__ out)           // zeroed by block 0 (finalize adds)
{
    __shared__ float sx[NUM_V], sy[NUM_V], sz[NUM_V];   // 6 KB
    __shared__ float4 sfA[FPC+4], sfB[FPC+4];
    __shared__ float  sfC[FPC+4];
    __shared__ int scnt;

    const int tid   = threadIdx.x;
    const int chunk = blockIdx.x & (NCHUNK-1);
    const int grp   = blockIdx.x >> 4;        // 0..63

    if (blockIdx.x == 0 && tid == 0) out[0] = 0.0f;

    // ---- camera basis ----
    const float ex = cam[0], ey = cam[1], ez = cam[2];
    float inv = 1.0f / (sqrtf(ex*ex + ey*ey + ez*ez) + 1e-8f);
    const float zx = -ex*inv, zy = -ey*inv, zz = -ez*inv;
    float xxr = zz, xyr = 0.0f, xzr = -zx;    // cross((0,1,0), z)
    inv = 1.0f / (sqrtf(xxr*xxr + xyr*xyr + xzr*xzr) + 1e-8f);
    const float xx = xxr*inv, xy = xyr*inv, xz = xzr*inv;
    float yxr = zy*xz - zz*xy;
    float yyr = zz*xx - zx*xz;
    float yzr = zx*xy - zy*xx;
    inv = 1.0f / (sqrtf(yxr*yxr + yyr*yyr + yzr*yzr) + 1e-8f);
    const float yx = yxr*inv, yy = yyr*inv, yz = yzr*inv;

    // ---- project vertices (2 per thread) ----
    for (int v = tid; v < NUM_V; v += 256) {
        float px = verts[3*v+0] - ex;
        float py = verts[3*v+1] - ey;
        float pz = verts[3*v+2] - ez;
        float vx = xx*px + xy*py + xz*pz;
        float vy = yx*px + yy*py + yz*pz;
        float vz = zx*px + zy*py + zz*pz;
        float denom = 1.0f / (vz*TAN_T + 1e-8f);
        sx[v] = vx*denom;
        sy[v] = vy*denom;
        sz[v] = vz;
    }
    __syncthreads();

    // ---- face constants ONCE (registers, tid<64); tile-independent ----
    float A[3], B[3], C[3];   // scaled by 100 = sqrt(1/SIGMA)
    bool valid = false;
    if (tid < FPC) {
        const int f = chunk*FPC + tid;
        int i0f = faces[3*f+0], i1f = faces[3*f+1], i2f = faces[3*f+2];
        float ax = sx[i0f], ay = sy[i0f], z0 = sz[i0f];
        float bx = sx[i1f], by = sy[i1f], z1 = sz[i1f];
        float cx = sx[i2f], cy = sy[i2f], z2 = sz[i2f];
        valid = (z0 > 0.001f && z1 > 0.001f && z2 > 0.001f);
        const float px_[3] = {ax, bx, cx}, py_[3] = {ay, by, cy};
        const float qx_[3] = {bx, cx, ax}, qy_[3] = {by, cy, ay};
        #pragma unroll
        for (int k = 0; k < 3; ++k) {
            float eex = qx_[k] - px_[k];
            float eey = qy_[k] - py_[k];
            float il = 100.0f / (sqrtf(eex*eex + eey*eey) + 1e-8f);
            A[k] = eex*il;
            B[k] = eey*il;
            C[k] = (eex*py_[k] - eey*px_[k])*il;
        }
    }

    // thread's pixel within a tile: wave = 8x8 sub-tile
    const int w = tid >> 6, l = tid & 63;
    const int lj = (w & 1)*8 + (l & 7);
    const int li = (w >> 1)*8 + (l >> 3);

    for (int k = 0; k < TPB; ++k) {
        const int tile = grp + NGRP*k;        // 4 tile-rows apart
        const int j0 = (tile & 15) * 16;
        const int i0 = (tile >> 4) * 16;

        __syncthreads();                      // prev iter done with sfA/scnt
        if (tid == 0) scnt = 0;
        __syncthreads();

        // ---- cull vs this tile's rect (exact affine corner bound) ----
        if (tid < FPC && valid) {
            const float xL = (j0 + 0.5f )*(2.0f/IMG_H) - 1.0f;
            const float xR = (j0 + 15.5f)*(2.0f/IMG_H) - 1.0f;
            const float yT = 1.0f - (i0 + 0.5f )*(2.0f/IMG_H);
            const float yB = 1.0f - (i0 + 15.5f)*(2.0f/IMG_H);
            float minmx = 3.0e38f, maxmn = -3.0e38f;
            #pragma unroll
            for (int e = 0; e < 3; ++e) {
                float dTL = A[e]*yT - B[e]*xL - C[e];
                float dTR = A[e]*yT - B[e]*xR - C[e];
                float dBL = A[e]*yB - B[e]*xL - C[e];
                float dBR = A[e]*yB - B[e]*xR - C[e];
                float mx = fmaxf(fmaxf(dTL, dTR), fmaxf(dBL, dBR));
                float mn = fminf(fminf(dTL, dTR), fminf(dBL, dBR));
                minmx = fminf(minmx, mx);
                maxmn = fmaxf(maxmn, mn);
            }
            bool keep = !((minmx <= DCULL_S) && (maxmn >= -DCULL_S));
            if (keep) {
                int s = atomicAdd(&scnt, 1);
                sfA[s] = make_float4(A[0], B[0], C[0], A[1]);
                sfB[s] = make_float4(B[1], C[1], A[2], B[2]);
                sfC[s] = C[2];
            }
        }
        __syncthreads();

        const int n = scnt;                   // block-uniform
        if (tid == 0) cnt[tile*NCHUNK + chunk] = n;
        if (n == 0) continue;                 // uniform branch; slice unread

        // pad to multiple of 4 with zero-contribution sentinels
        const int npad = (4 - (n & 3)) & 3;
        if (tid < npad) {
            const int s = n + tid;
            sfA[s] = make_float4(0.0f, 0.0f, 1e30f, 0.0f);
            sfB[s] = make_float4(0.0f, -1e30f, 0.0f, 0.0f);
            sfC[s] = 0.0f;
        }
        __syncthreads();
        const int ng = (n + 3) & ~3;

        const float qx = (j0 + lj + 0.5f)*(2.0f/IMG_H) - 1.0f;
        const float qy = 1.0f - (i0 + li + 0.5f)*(2.0f/IMG_H);

        float acc = 0.0f;
        for (int g = 0; g < ng; g += 4) {
            float dist4[4];
            #pragma unroll
            for (int u = 0; u < 4; ++u) {
                float4 w0 = sfA[g+u];
                float4 w1 = sfB[g+u];
                float  c2 = sfC[g+u];
                float d0 = fmaf(w0.x, qy, -fmaf(w0.y, qx, w0.z));
                float d1 = fmaf(w0.w, qy, -fmaf(w1.x, qx, w1.y));
                float d2 = fmaf(w1.z, qy, -fmaf(w1.w, qx, c2));
                float dmin = fminf(fminf(d0, d1), d2);
                float dmax = fmaxf(fmaxf(d0, d1), d2);
                dist4[u] = fmaxf(dmin, -dmax);   // = 100 * true dist
            }
            float gm = fmaxf(fmaxf(dist4[0], dist4[1]), fmaxf(dist4[2], dist4[3]));
            if (__any(gm > DCULL_S)) {
                #pragma unroll
                for (int u = 0; u < 4; ++u) {
                    float dist = dist4[u];
                    float s  = dist * fabsf(dist);     // true dist*|dist|/SIGMA
                    float e2 = __builtin_exp2f(-fabsf(s) * 1.44269504f);
                    float lg = __builtin_log2f(1.0f + e2);
                    float sp = fmaf(lg, 0.69314718f, fmaxf(s, 0.0f));
                    acc += fmaxf(-sp, LOG_EPS);
                }
            }
        }
        slices[(tile*NCHUNK + chunk)*256 + li*16 + lj] = acc;
    }
}

// ---------------------------------------------------------------------------
// Finalize: one block per tile. Sum only chunks with cnt>0 (block-uniform
// branch; tiles with no survivors read zero slices -> alpha = 0 exactly),
// squared error vs image_ref, block reduce, one atomicAdd.
// ---------------------------------------------------------------------------
__global__ __launch_bounds__(256) void finalize_kernel(
    const float* __restrict__ image_ref,
    const float* __restrict__ slices,
    const int*   __restrict__ cnt,
    const float* __restrict__ cam,
    float* __restrict__ out)
{
    __shared__ float wsum[4];
    const int tid  = threadIdx.x;
    const int tile = blockIdx.x;
    const int j0 = (tile & 15) * 16;
    const int i0 = (tile >> 4) * 16;
    const int li = tid >> 4, lj = tid & 15;
    const int p  = (i0 + li)*IMG_H + (j0 + lj);

    float lsum = 0.0f;
    #pragma unroll
    for (int c = 0; c < NCHUNK; ++c) {
        if (cnt[tile*NCHUNK + c] > 0)              // block-uniform branch
            lsum += slices[(tile*NCHUNK + c)*256 + tid];
    }
    float alpha = 1.0f - __expf(lsum);
    float diff  = image_ref[p] - alpha;
    float sq = diff * diff;

    #pragma unroll
    for (int off = 32; off > 0; off >>= 1) sq += __shfl_down(sq, off, 64);
    if ((tid & 63) == 0) wsum[tid >> 6] = sq;
    __syncthreads();
    if (tid == 0) {
        float ex = cam[0], ey = cam[1], ez = cam[2];
        float dist = sqrtf(ex*ex + ey*ey + ez*ez);
        float pen = fmaxf(6.0f - dist, 0.0f);
        float bs = (wsum[0] + wsum[1]) + (wsum[2] + wsum[3]);
        atomicAdd(out, bs * (1.0f + pen));
    }
}

extern "C" void kernel_launch(void* const* d_in, const int* in_sizes, int n_in,
                              void* d_out, int out_size, void* d_ws, size_t ws_size,
                              hipStream_t stream)
{
    const float* verts     = (const float*)d_in[0];  // (1,512,3)
    const int*   faces     = (const int*)  d_in[1];  // (1,1024,3)
    const float* image_ref = (const float*)d_in[2];  // (256,256)
    const float* cam       = (const float*)d_in[3];  // (3,)

    float* slices = (float*)d_ws;                        // NTILE*NCHUNK*256 f32 = 4 MB
    int*   cnt    = (int*)((char*)d_ws + NTILE*NCHUNK*256*4); // 16 KB
    float* out    = (float*)d_out;

    render_kernel  <<<NGRP*NCHUNK, 256, 0, stream>>>(verts, faces, cam,
                                                     slices, cnt, out);
    finalize_kernel<<<NTILE,       256, 0, stream>>>(image_ref, slices, cnt,
                                                     cam, out);
}

// Round 9
// 79.542 us; speedup vs baseline: 13.3286x; 1.0497x over previous
//
#include <hip/hip_runtime.h>
#include <math.h>

#define NUM_V 512
#define NUM_F 1024
#define IMG_H 256
#define NPIX (IMG_H*IMG_H)
#define NCHUNK 16
#define FPC (NUM_F/NCHUNK)        // 64 faces per chunk
#define TAN_T 0.57735026919f      // tan(30 deg)
#define LOG_EPS  -13.8155106f     // log(1e-6)
// Edge constants are pre-scaled by 100 = sqrt(1/SIGMA), so s = d'*|d'| directly.
#define DCULL_S  -3.72f           // scaled dist <= -3.72  =>  |term| < 1e-6

// R9 = exact revert to R5 (best measured: 79.5 us). R6 (spin-wait fusion,
// 334 us), R7 (arrival-counter fusion, 1036 us), and R8 (4-tiles-per-block
// prologue amortization, 83.5 us) all regressed. The remaining time is
// dominated by the harness's 256 MB d_ws poison fill (~39.5 us at 85% of
// achievable HBM BW) plus input restores and graph replay -- outside kernel
// control.
//
// Render. Grid = 256 pixel-tiles (16x16 px) x NCHUNK face-chunks, chunk in
// the fast-varying blockIdx bits. Per block:
//   prologue: project 512 verts, build 100x-scaled edge constants for the
//             chunk's 64 faces, cull vs tile rect (exact affine corner
//             bound), compact survivors to LDS (packed 9 floats/face).
//   n==0 (the vast majority): write cnt=0, exit. Slice left poisoned --
//             finalize never reads slices with cnt==0.
//   n>0:      pad to multiple of 4 with zero-contribution sentinels, loop
//             groups of 4 over the 16x16 tile (wave = 8x8 sub-tile for
//             coherent transcendental skip), store 256-float slice.
// Block 0 zeroes out[0] (finalize atomicAdds into it; stream-ordered).
__global__ __launch_bounds__(256, 8) void render_kernel(
    const float* __restrict__ verts,   // (NUM_V,3)
    const int*   __restrict__ faces,   // (NUM_F,3)
    const float* __restrict__ cam,     // (3,)
    float* __restrict__ slices,        // 256*NCHUNK*256 floats (sparse-written)
    int*   __restrict__ cnt,           // 256*NCHUNK ints (always written)
    float* __restrict__ out)
{
    __shared__ float sx[NUM_V], sy[NUM_V], sz[NUM_V];   // 6 KB
    __shared__ float4 sfA[FPC+4], sfB[FPC+4];           // 2.1 KB
    __shared__ float  sfC[FPC+4];
    __shared__ int scnt;
    const int tid   = threadIdx.x;
    const int chunk = blockIdx.x & (NCHUNK-1);
    const int tile  = blockIdx.x / NCHUNK;

    if (blockIdx.x == 0 && tid == 0) out[0] = 0.0f;
    if (tid == 0) scnt = 0;

    // ---- camera basis ----
    const float ex = cam[0], ey = cam[1], ez = cam[2];
    float inv = 1.0f / (sqrtf(ex*ex + ey*ey + ez*ez) + 1e-8f);
    const float zx = -ex*inv, zy = -ey*inv, zz = -ez*inv;
    float xxr = zz, xyr = 0.0f, xzr = -zx;    // cross((0,1,0), z)
    inv = 1.0f / (sqrtf(xxr*xxr + xyr*xyr + xzr*xzr) + 1e-8f);
    const float xx = xxr*inv, xy = xyr*inv, xz = xzr*inv;
    float yxr = zy*xz - zz*xy;
    float yyr = zz*xx - zx*xz;
    float yzr = zx*xy - zy*xx;
    inv = 1.0f / (sqrtf(yxr*yxr + yyr*yyr + yzr*yzr) + 1e-8f);
    const float yx = yxr*inv, yy = yyr*inv, yz = yzr*inv;

    // ---- project vertices (2 per thread) ----
    for (int v = tid; v < NUM_V; v += 256) {
        float px = verts[3*v+0] - ex;
        float py = verts[3*v+1] - ey;
        float pz = verts[3*v+2] - ez;
        float vx = xx*px + xy*py + xz*pz;
        float vy = yx*px + yy*py + yz*pz;
        float vz = zx*px + zy*py + zz*pz;
        float denom = 1.0f / (vz*TAN_T + 1e-8f);
        sx[v] = vx*denom;
        sy[v] = vy*denom;
        sz[v] = vz;
    }
    __syncthreads();   // covers scnt init too

    // ---- tile rect (pixel-center corners; d affine -> corners bound it) ----
    const int j0 = (tile & 15) * 16;
    const int i0 = (tile >> 4) * 16;
    const float xL = (j0 + 0.5f )*(2.0f/IMG_H) - 1.0f;
    const float xR = (j0 + 15.5f)*(2.0f/IMG_H) - 1.0f;
    const float yT = 1.0f - (i0 + 0.5f )*(2.0f/IMG_H);
    const float yB = 1.0f - (i0 + 15.5f)*(2.0f/IMG_H);

    // ---- cull + compact this chunk's faces (one per thread, tid<64) ----
    if (tid < FPC) {
        const int f = chunk*FPC + tid;
        int i0f = faces[3*f+0], i1f = faces[3*f+1], i2f = faces[3*f+2];
        float ax = sx[i0f], ay = sy[i0f], z0 = sz[i0f];
        float bx = sx[i1f], by = sy[i1f], z1 = sz[i1f];
        float cx = sx[i2f], cy = sy[i2f], z2 = sz[i2f];
        bool keep = (z0 > 0.001f && z1 > 0.001f && z2 > 0.001f);

        float A[3], B[3], C[3];   // scaled by 100 = sqrt(1/SIGMA)
        const float px_[3] = {ax, bx, cx}, py_[3] = {ay, by, cy};
        const float qx_[3] = {bx, cx, ax}, qy_[3] = {by, cy, ay};
        #pragma unroll
        for (int k = 0; k < 3; ++k) {
            float eex = qx_[k] - px_[k];
            float eey = qy_[k] - py_[k];
            float il = 100.0f / (sqrtf(eex*eex + eey*eey) + 1e-8f);
            A[k] = eex*il;
            B[k] = eey*il;
            C[k] = (eex*py_[k] - eey*px_[k])*il;
        }

        if (keep) {
            // skip iff (min_k max_q d_k <= DCULL_S) && (max_k min_q d_k >= -DCULL_S)
            float minmx = 3.0e38f, maxmn = -3.0e38f;
            #pragma unroll
            for (int k = 0; k < 3; ++k) {
                float dTL = A[k]*yT - B[k]*xL - C[k];
                float dTR = A[k]*yT - B[k]*xR - C[k];
                float dBL = A[k]*yB - B[k]*xL - C[k];
                float dBR = A[k]*yB - B[k]*xR - C[k];
                float mx = fmaxf(fmaxf(dTL, dTR), fmaxf(dBL, dBR));
                float mn = fminf(fminf(dTL, dTR), fminf(dBL, dBR));
                minmx = fminf(minmx, mx);
                maxmn = fmaxf(maxmn, mn);
            }
            keep = !((minmx <= DCULL_S) && (maxmn >= -DCULL_S));
        }
        if (keep) {
            int s = atomicAdd(&scnt, 1);
            sfA[s] = make_float4(A[0], B[0], C[0], A[1]);
            sfB[s] = make_float4(B[1], C[1], A[2], B[2]);
            sfC[s] = C[2];
        }
    }
    __syncthreads();

    const int n = scnt;
    if (tid == 0) cnt[tile*NCHUNK + chunk] = n;
    if (n == 0) return;   // ~99% of blocks exit; slice stays unread-poisoned

    // pad to multiple of 4 with sentinels: dist=-1e30 -> contributes exactly 0
    const int npad = (4 - (n & 3)) & 3;
    if (tid < npad) {
        const int s = n + tid;
        sfA[s] = make_float4(0.0f, 0.0f, 1e30f, 0.0f);
        sfB[s] = make_float4(0.0f, -1e30f, 0.0f, 0.0f);
        sfC[s] = 0.0f;
    }
    __syncthreads();
    const int ng = (n + 3) & ~3;

    // ---- pixel for this thread: wave = 8x8 sub-tile ----
    const int w = tid >> 6, l = tid & 63;
    const int lj = (w & 1)*8 + (l & 7);
    const int li = (w >> 1)*8 + (l >> 3);
    const int j = j0 + lj, i = i0 + li;
    const float qx = (j + 0.5f)*(2.0f/IMG_H) - 1.0f;
    const float qy = 1.0f - (i + 0.5f)*(2.0f/IMG_H);

    float acc = 0.0f;
    for (int g = 0; g < ng; g += 4) {
        float dist4[4];
        #pragma unroll
        for (int u = 0; u < 4; ++u) {
            float4 w0 = sfA[g+u];
            float4 w1 = sfB[g+u];
            float  c2 = sfC[g+u];
            float d0 = fmaf(w0.x, qy, -fmaf(w0.y, qx, w0.z));
            float d1 = fmaf(w0.w, qy, -fmaf(w1.x, qx, w1.y));
            float d2 = fmaf(w1.z, qy, -fmaf(w1.w, qx, c2));
            float dmin = fminf(fminf(d0, d1), d2);
            float dmax = fmaxf(fmaxf(d0, d1), d2);
            dist4[u] = fmaxf(dmin, -dmax);   // = 100 * true dist
        }
        float gm = fmaxf(fmaxf(dist4[0], dist4[1]), fmaxf(dist4[2], dist4[3]));
        if (__any(gm > DCULL_S)) {
            #pragma unroll
            for (int u = 0; u < 4; ++u) {
                float dist = dist4[u];
                float s  = dist * fabsf(dist);        // = true dist*|dist|/SIGMA
                float e2 = __builtin_exp2f(-fabsf(s) * 1.44269504f);
                float lg = __builtin_log2f(1.0f + e2);
                float sp = fmaf(lg, 0.69314718f, fmaxf(s, 0.0f));
                acc += fmaxf(-sp, LOG_EPS);
            }
        }
    }
    // slice layout: [(tile*NCHUNK+chunk)*256 + li*16+lj] -- contiguous per block
    slices[(tile*NCHUNK + chunk)*256 + li*16 + lj] = acc;
}

// ---------------------------------------------------------------------------
// Finalize: one block per tile. Sum only chunks with cnt>0 (block-uniform
// branch; empty tiles read zero slice data -> alpha = 0 exactly), then
// squared error vs image_ref, block reduce, one atomicAdd.
// ---------------------------------------------------------------------------
__global__ __launch_bounds__(256) void finalize_kernel(
    const float* __restrict__ image_ref,
    const float* __restrict__ slices,
    const int*   __restrict__ cnt,
    const float* __restrict__ cam,
    float* __restrict__ out)
{
    __shared__ float wsum[4];
    const int tid  = threadIdx.x;
    const int tile = blockIdx.x;
    const int j0 = (tile & 15) * 16;
    const int i0 = (tile >> 4) * 16;
    const int li = tid >> 4, lj = tid & 15;        // straight map: coalesced
    const int p  = (i0 + li)*IMG_H + (j0 + lj);

    float lsum = 0.0f;
    #pragma unroll
    for (int c = 0; c < NCHUNK; ++c) {
        if (cnt[tile*NCHUNK + c] > 0)              // block-uniform branch
            lsum += slices[(tile*NCHUNK + c)*256 + tid];
    }
    float alpha = 1.0f - __expf(lsum);
    float diff  = image_ref[p] - alpha;
    float sq = diff * diff;

    #pragma unroll
    for (int off = 32; off > 0; off >>= 1) sq += __shfl_down(sq, off, 64);
    if ((tid & 63) == 0) wsum[tid >> 6] = sq;
    __syncthreads();
    if (tid == 0) {
        float ex = cam[0], ey = cam[1], ez = cam[2];
        float dist = sqrtf(ex*ex + ey*ey + ez*ez);
        float pen = fmaxf(6.0f - dist, 0.0f);
        float bs = (wsum[0] + wsum[1]) + (wsum[2] + wsum[3]);
        atomicAdd(out, bs * (1.0f + pen));
    }
}

extern "C" void kernel_launch(void* const* d_in, const int* in_sizes, int n_in,
                              void* d_out, int out_size, void* d_ws, size_t ws_size,
                              hipStream_t stream)
{
    const float* verts     = (const float*)d_in[0];  // (1,512,3)
    const int*   faces     = (const int*)  d_in[1];  // (1,1024,3)
    const float* image_ref = (const float*)d_in[2];  // (256,256)
    const float* cam       = (const float*)d_in[3];  // (3,)

    float* slices = (float*)d_ws;                        // 256*NCHUNK*256 f32 = 4 MB
    int*   cnt    = (int*)((char*)d_ws + 256*NCHUNK*256*sizeof(float)); // 16 KB
    float* out    = (float*)d_out;

    render_kernel  <<<256*NCHUNK, 256, 0, stream>>>(verts, faces, cam,
                                                    slices, cnt, out);
    finalize_kernel<<<256,        256, 0, stream>>>(image_ref, slices, cnt,
                                                    cam, out);
}